// Round 10
// baseline (999.986 us; speedup 1.0000x reference)
//
#include <hip/hip_runtime.h>

// Math (verified): softmax over a size-1 axis == 1, so
//   out = relu(x @ (gamma*W3 + W4)^T),  x:(B,20), fused M:(200,20)
// Memory floor: 210 MB out write + 21 MB x read => ~34-37 us.
//
// v9 diag (REPEAT=3) finally unblinded the counters: VGPR 84, VALUBusy 39%,
// hbm 3.9 TB/s (58% of achievable), bank conflicts 0, steady main loop
// ~48 us/pass vs 34 us write floor. Nothing saturated => store-retire MLP
// limit: 2 nontemporal stores in flight per wave (acc reuse distance 2),
// nt = no L2 allocate = full-memory retire latency. Wave store throughput
// ~0.8 B/cy * ~8 waves/CU ~ 6 B/cy/CU = exactly the measured 3.9 TB/s.
//
// v10: (a) 4 rotating accumulators, 4 rows computed then 4 stores issued
// back-to-back -> reuse distance 4 (vmcnt(3)), 2x in-flight stores;
// (b) stores are PLAIN (L2-allocating, retire on L2 ack like the 6.7 TB/s
// harness fills; L2->HBM writeback is async). nt kept on x staging loads
// only. __launch_bounds__(256,5) caps VGPR ~102 (measured 84 + 16 accs).

#define BATCH          262144
#define DICT           20
#define COLS           200                        // NUM_HEADS * DICT
#define NTHREADS       256                        // 4 waves
#define ROWS_PER_BLOCK 128
#define ROWS_PER_WAVE  32
#define NBLOCKS        (BATCH / ROWS_PER_BLOCK)   // 2048

typedef float f32x4 __attribute__((ext_vector_type(4)));

__global__ __launch_bounds__(NTHREADS, 5)
void attn_v10_kernel(const float* __restrict__ x,
                     const float* __restrict__ W3,
                     const float* __restrict__ W4,
                     const float* __restrict__ gamma,
                     float* __restrict__ out)
{
    __shared__ f32x4 ldsX[ROWS_PER_BLOCK * 5];   // 10 KB x tile

    const int t = threadIdx.x;

    // Stage x tile (x is read once chip-wide -> nt load is fine).
    const f32x4* xg = (const f32x4*)(x + (size_t)blockIdx.x * ROWS_PER_BLOCK * DICT);
    for (int i = t; i < ROWS_PER_BLOCK * 5; i += NTHREADS)
        ldsX[i] = __builtin_nontemporal_load(&xg[i]);
    __syncthreads();

    const int lane = t & 63;
    const int wv   = t >> 6;          // wave = row group (wave-uniform rows)
    if (lane >= 50) return;           // after the only barrier -> legal

    const float g   = gamma[0];
    const int   cf4 = lane;           // float4-column strip in [0,50)

    // Fused M = g*W3 + W4 for this thread's 4 columns, from global
    // (16 KB, L2-resident; plain loads so it STAYS L2-resident).
    f32x4 m[4][5];
#pragma unroll
    for (int c = 0; c < 4; ++c) {
        const f32x4* a = (const f32x4*)(W3 + (4 * cf4 + c) * DICT);
        const f32x4* b = (const f32x4*)(W4 + (4 * cf4 + c) * DICT);
#pragma unroll
        for (int k = 0; k < 5; ++k) {
            f32x4 p = a[k], q = b[k], r;
            r.x = fmaf(g, p.x, q.x); r.y = fmaf(g, p.y, q.y);
            r.z = fmaf(g, p.z, q.z); r.w = fmaf(g, p.w, q.w);
            m[c][k] = r;
        }
    }

    const int row0 = blockIdx.x * ROWS_PER_BLOCK + wv * ROWS_PER_WAVE;
    const f32x4* xl = &ldsX[wv * ROWS_PER_WAVE * 5];   // wave-uniform base
    f32x4* op = (f32x4*)(out + (size_t)row0 * COLS) + cf4;  // 50 f4/row

#define DOT4(ACC, XP)                                          \
    {                                                          \
        float* ap_ = (float*)&(ACC);                           \
        _Pragma("unroll")                                      \
        for (int c = 0; c < 4; ++c) {                          \
            float p0 = 0.f, p1 = 0.f;                          \
            _Pragma("unroll")                                  \
            for (int k = 0; k < 5; ++k) {                      \
                p0 = fmaf(m[c][k].x, (XP)[k].x, p0);           \
                p1 = fmaf(m[c][k].y, (XP)[k].y, p1);           \
                p0 = fmaf(m[c][k].z, (XP)[k].z, p0);           \
                p1 = fmaf(m[c][k].w, (XP)[k].w, p1);           \
            }                                                  \
            ap_[c] = fmaxf(p0 + p1, 0.f);                      \
        }                                                      \
    }

    // 4 rows per body: compute a0,a1,b0,b1 (all live), then 4 back-to-back
    // stores. Acc reuse distance = 4 stores -> vmcnt(3) waits, 2x the
    // in-flight stores of v6. x rows double-buffered xv (r,r+1) / xn (r+2,r+3).
    f32x4 xv[10], xn[10];
#pragma unroll
    for (int k = 0; k < 10; ++k) xv[k] = xl[k];      // rows 0,1

    for (int r = 0; r < ROWS_PER_WAVE; r += 4) {
        // prefetch rows r+2, r+3 ahead of the first FMA block
#pragma unroll
        for (int k = 0; k < 10; ++k) xn[k] = xl[(r + 2) * 5 + k];

        f32x4 a0, a1, b0, b1;
        DOT4(a0, (&xv[0]))
        DOT4(a1, (&xv[5]))

        // prefetch rows r+4, r+5 ahead of the second FMA block
        if (r + 4 < ROWS_PER_WAVE) {
#pragma unroll
            for (int k = 0; k < 10; ++k) xv[k] = xl[(r + 4) * 5 + k];
        }

        DOT4(b0, (&xn[0]))
        DOT4(b1, (&xn[5]))

        // store burst: 4 independent plain stores (L2-allocating)
        op[(size_t)(r + 0) * 50] = a0;
        op[(size_t)(r + 1) * 50] = a1;
        op[(size_t)(r + 2) * 50] = b0;
        op[(size_t)(r + 3) * 50] = b1;
    }
#undef DOT4
}

extern "C" void kernel_launch(void* const* d_in, const int* in_sizes, int n_in,
                              void* d_out, int out_size, void* d_ws, size_t ws_size,
                              hipStream_t stream) {
    const float* x     = (const float*)d_in[0];
    // d_in[1] = W1, d_in[2] = W2 : mathematically unused (softmax over size-1 axis)
    const float* W3    = (const float*)d_in[3];
    const float* W4    = (const float*)d_in[4];
    const float* gamma = (const float*)d_in[5];
    float* out = (float*)d_out;

    attn_v10_kernel<<<NBLOCKS, NTHREADS, 0, stream>>>(x, W3, W4, gamma, out);
}

// Round 11
// 310.049 us; speedup vs baseline: 3.2253x; 3.2253x over previous
//
#include <hip/hip_runtime.h>

// Math (verified): softmax over a size-1 axis == 1, so
//   out = relu(x @ (gamma*W3 + W4)^T),  x:(B,20), fused M:(200,20)
// Memory floor: 210 MB out write + 21 MB x read => ~34-37 us.
//
// v9 diag: VALUBusy 39%, hbm 3.9 TB/s, conflicts 0, occ 24%, VGPR 84 ->
// store-retire MLP limit (2 in-flight stores/wave at acc reuse distance 2).
// v10 FAILED by spilling: __launch_bounds__(256,5) cap (~102) < working set
// (m 80 + x-bufs 80 + accs 16) -> VGPR 48 + 3.3 GB scratch traffic/dispatch.
//
// v11 = same theory, spill-safe:
//  - v6's proven 2-buffer x pipeline (compiler folds it; 84 VGPR at bound 3)
//    extended to a 4-row body: 4 accumulators, 4 back-to-back PLAIN stores
//    (L2-allocating, retire on L2 ack like the 6.7 TB/s fills) -> reuse
//    distance 4, 2x in-flight stores per wave. nt only on x staging loads.
//  - __launch_bounds__(256,3): the proven no-spill regime.
//  - ROWS_PER_BLOCK 256 (64 rows/wave, 1024 blocks): halves chip-wide
//    prologue (M-fuse + barrier) cost. LDS 20 KB.
// Spill tripwire for next round: FETCH_SIZE must be ~10 MB, not >100 MB.

#define BATCH          262144
#define DICT           20
#define COLS           200                        // NUM_HEADS * DICT
#define NTHREADS       256                        // 4 waves
#define ROWS_PER_BLOCK 256
#define ROWS_PER_WAVE  64
#define NBLOCKS        (BATCH / ROWS_PER_BLOCK)   // 1024

typedef float f32x4 __attribute__((ext_vector_type(4)));

__global__ __launch_bounds__(NTHREADS, 3)
void attn_v11_kernel(const float* __restrict__ x,
                     const float* __restrict__ W3,
                     const float* __restrict__ W4,
                     const float* __restrict__ gamma,
                     float* __restrict__ out)
{
    __shared__ f32x4 ldsX[ROWS_PER_BLOCK * 5];   // 20 KB x tile

    const int t = threadIdx.x;

    // Stage x tile (read once chip-wide -> nt loads).
    const f32x4* xg = (const f32x4*)(x + (size_t)blockIdx.x * ROWS_PER_BLOCK * DICT);
    for (int i = t; i < ROWS_PER_BLOCK * 5; i += NTHREADS)   // 1280 f4, 5 iters
        ldsX[i] = __builtin_nontemporal_load(&xg[i]);
    __syncthreads();

    const int lane = t & 63;
    const int wv   = t >> 6;          // wave = row group (wave-uniform rows)
    if (lane >= 50) return;           // after the only barrier -> legal

    const float g   = gamma[0];
    const int   cf4 = lane;           // float4-column strip in [0,50)

    // Fused M = g*W3 + W4 for this thread's 4 columns, from global
    // (16 KB, L2-resident). 80 VGPRs, amortized over 64 rows.
    f32x4 m[4][5];
#pragma unroll
    for (int c = 0; c < 4; ++c) {
        const f32x4* a = (const f32x4*)(W3 + (4 * cf4 + c) * DICT);
        const f32x4* b = (const f32x4*)(W4 + (4 * cf4 + c) * DICT);
#pragma unroll
        for (int k = 0; k < 5; ++k) {
            f32x4 p = a[k], q = b[k], r;
            r.x = fmaf(g, p.x, q.x); r.y = fmaf(g, p.y, q.y);
            r.z = fmaf(g, p.z, q.z); r.w = fmaf(g, p.w, q.w);
            m[c][k] = r;
        }
    }

    const int row0 = blockIdx.x * ROWS_PER_BLOCK + wv * ROWS_PER_WAVE;
    const f32x4* xl = &ldsX[wv * ROWS_PER_WAVE * 5];   // wave-uniform base
    f32x4* op = (f32x4*)(out + (size_t)row0 * COLS) + cf4;  // 50 f4/row

#define DOT4(ACC, XP)                                          \
    {                                                          \
        float* ap_ = (float*)&(ACC);                           \
        _Pragma("unroll")                                      \
        for (int c = 0; c < 4; ++c) {                          \
            float p0 = 0.f, p1 = 0.f;                          \
            _Pragma("unroll")                                  \
            for (int k = 0; k < 5; ++k) {                      \
                p0 = fmaf(m[c][k].x, (XP)[k].x, p0);           \
                p1 = fmaf(m[c][k].y, (XP)[k].y, p1);           \
                p0 = fmaf(m[c][k].z, (XP)[k].z, p0);           \
                p1 = fmaf(m[c][k].w, (XP)[k].w, p1);           \
            }                                                  \
            ap_[c] = fmaxf(p0 + p1, 0.f);                      \
        }                                                      \
    }

    // 4-row body, only TWO live x buffers (xv/xn ping-pong, as in v6 --
    // the compiler folds these; keeps VGPR < 100). Stores deferred to a
    // burst of 4 plain stores -> 4 outstanding per wave.
    f32x4 xv[5], xn[5];
#pragma unroll
    for (int k = 0; k < 5; ++k) xv[k] = xl[k];       // row 0

    for (int r = 0; r < ROWS_PER_WAVE; r += 4) {
        f32x4 a0, a1, a2, a3;

#pragma unroll
        for (int k = 0; k < 5; ++k) xn[k] = xl[(r + 1) * 5 + k];
        DOT4(a0, xv)                                  // row r

#pragma unroll
        for (int k = 0; k < 5; ++k) xv[k] = xl[(r + 2) * 5 + k];
        DOT4(a1, xn)                                  // row r+1

#pragma unroll
        for (int k = 0; k < 5; ++k) xn[k] = xl[(r + 3) * 5 + k];
        DOT4(a2, xv)                                  // row r+2

        if (r + 4 < ROWS_PER_WAVE) {
#pragma unroll
            for (int k = 0; k < 5; ++k) xv[k] = xl[(r + 4) * 5 + k];
        }
        DOT4(a3, xn)                                  // row r+3

        // store burst: 4 independent plain stores, contiguous 800 B each
        op[(size_t)(r + 0) * 50] = a0;
        op[(size_t)(r + 1) * 50] = a1;
        op[(size_t)(r + 2) * 50] = a2;
        op[(size_t)(r + 3) * 50] = a3;
    }
#undef DOT4
}

extern "C" void kernel_launch(void* const* d_in, const int* in_sizes, int n_in,
                              void* d_out, int out_size, void* d_ws, size_t ws_size,
                              hipStream_t stream) {
    const float* x     = (const float*)d_in[0];
    // d_in[1] = W1, d_in[2] = W2 : mathematically unused (softmax over size-1 axis)
    const float* W3    = (const float*)d_in[3];
    const float* W4    = (const float*)d_in[4];
    const float* gamma = (const float*)d_in[5];
    float* out = (float*)d_out;

    attn_v11_kernel<<<NBLOCKS, NTHREADS, 0, stream>>>(x, W3, W4, gamma, out);
}